// Round 13
// baseline (289.839 us; speedup 1.0000x reference)
//
#include <hip/hip_runtime.h>
#include <hip/hip_bf16.h>

typedef __hip_bfloat16 bf16;
typedef short bf16x8 __attribute__((ext_vector_type(8)));
typedef float f32x4 __attribute__((ext_vector_type(4)));

// B=4, T=2048, D=1024, H=16, HD=64

static __device__ __forceinline__ void glds16(const bf16* g, bf16* l) {
  __builtin_amdgcn_global_load_lds(
      (const __attribute__((address_space(1))) void*)g,
      (__attribute__((address_space(3))) void*)l, 16, 0, 0);
}

static __device__ __forceinline__ unsigned short f2b(float f) {
  return __builtin_bit_cast(unsigned short, __float2bfloat16(f));
}
static __device__ __forceinline__ float b2f(unsigned int u16bits) {
  return __builtin_bit_cast(float, u16bits << 16);
}
// 2^x via the clang builtin (lowers to v_exp_f32 with compiler-managed hazards)
static __device__ __forceinline__ float ex2(float x) {
  return __builtin_amdgcn_exp2f(x);
}

// ---------------- fp32 -> bf16 convert, 4 elems/thread ----------------
__global__ void k_convert(const float* __restrict__ in, unsigned short* __restrict__ out, int n4) {
  int i = blockIdx.x * 256 + threadIdx.x;
  if (i >= n4) return;
  float4 v = reinterpret_cast<const float4*>(in)[i];
  ushort4 o;
  o.x = f2b(v.x); o.y = f2b(v.y); o.z = f2b(v.z); o.w = f2b(v.w);
  reinterpret_cast<ushort4*>(out)[i] = o;
}

// ---------------- transpose R x C fp32  ->  C x R bf16 ----------------
__global__ void k_transpose(const float* __restrict__ in, bf16* __restrict__ out, int R, int C) {
  __shared__ float t[32][33];
  int c0 = blockIdx.x * 32, r0 = blockIdx.y * 32;
  int tx = threadIdx.x, ty = threadIdx.y;  // block (32,8)
  #pragma unroll
  for (int j = 0; j < 32; j += 8)
    t[ty + j][tx] = in[(size_t)(r0 + ty + j) * C + c0 + tx];
  __syncthreads();
  #pragma unroll
  for (int j = 0; j < 32; j += 8)
    out[(size_t)(c0 + ty + j) * R + r0 + tx] = __float2bfloat16(t[tx][ty + j]);
}

// ---------------- GEMM: C = A(M x 1024) * Bt(N x 1024)^T + bias ----------------
// EPI 0: scatter to Qh/Kh[b][h][t][d], Vt[b][h][d][t] (bf16, +b_qkv)
// EPI 1: Out fp32 [m][1024] (+b_fc)
template<int EPI>
__global__ __launch_bounds__(256, 2)
void k_gemm(const bf16* __restrict__ A, const bf16* __restrict__ Bt,
            const float* __restrict__ bias,
            bf16* __restrict__ Qh, bf16* __restrict__ Kh, bf16* __restrict__ Vt,
            float* __restrict__ Out)
{
  constexpr int K = 1024;
  __shared__ bf16 sA[128 * 32];
  __shared__ bf16 sB[128 * 32];
  const int tid = threadIdx.x;
  const int wv = tid >> 6, lane = tid & 63;
  const int wr = wv >> 1, wc = wv & 1;
  const int l4 = lane >> 4, l15 = lane & 15;

  // XCD-aware bijective swizzle (nwg % 8 == 0 for both grids: 1536, 512)
  const int nbx = gridDim.x;
  const int nwg = nbx * gridDim.y;
  const int flat = blockIdx.y * nbx + blockIdx.x;
  const int cpx = nwg >> 3;
  const int swz = (flat & 7) * cpx + (flat >> 3);
  const int bx = swz % nbx;
  const int by = swz / nbx;

  const int srow = lane >> 2;         // 0..15
  const int scol = (lane & 3) * 8;    // element offset 0,8,16,24
  const bf16* gA0 = A  + (size_t)(by * 128 + wv * 16 + srow) * K + scol;
  const bf16* gB0 = Bt + (size_t)(bx * 128 + wv * 16 + srow) * K + scol;
  bf16* lA0 = sA + wv * 16 * 32;      // wave-uniform LDS base; HW adds lane*16B
  bf16* lB0 = sB + wv * 16 * 32;

  f32x4 acc[4][4];
  #pragma unroll
  for (int i = 0; i < 4; ++i)
    #pragma unroll
    for (int j = 0; j < 4; ++j) acc[i][j] = f32x4{0.f, 0.f, 0.f, 0.f};

  for (int kb = 0; kb < K; kb += 32) {
    glds16(gA0 + kb,                   lA0);
    glds16(gA0 + kb + (size_t)64 * K,  lA0 + 64 * 32);
    glds16(gB0 + kb,                   lB0);
    glds16(gB0 + kb + (size_t)64 * K,  lB0 + 64 * 32);
    __syncthreads();
    bf16x8 af[4], bfr[4];
    #pragma unroll
    for (int i = 0; i < 4; ++i)
      af[i] = *reinterpret_cast<const bf16x8*>(sA + (wr * 64 + i * 16 + l15) * 32 + l4 * 8);
    #pragma unroll
    for (int j = 0; j < 4; ++j)
      bfr[j] = *reinterpret_cast<const bf16x8*>(sB + (wc * 64 + j * 16 + l15) * 32 + l4 * 8);
    #pragma unroll
    for (int i = 0; i < 4; ++i)
      #pragma unroll
      for (int j = 0; j < 4; ++j)
        acc[i][j] = __builtin_amdgcn_mfma_f32_16x16x32_bf16(af[i], bfr[j], acc[i][j], 0, 0, 0);
    __syncthreads();
  }

  if (EPI == 0) {
    #pragma unroll
    for (int j = 0; j < 4; ++j) {
      const int n = bx * 128 + wc * 64 + j * 16 + l15;
      const float bj = bias[n];
      const int s = n >> 10;
      const int hh = (n >> 6) & 15;
      const int d = n & 63;
      #pragma unroll
      for (int i = 0; i < 4; ++i) {
        #pragma unroll
        for (int r = 0; r < 4; ++r) {
          const int m = by * 128 + wr * 64 + i * 16 + l4 * 4 + r;
          const int bb = m >> 11, t = m & 2047;
          const bf16 o = __float2bfloat16(acc[i][j][r] + bj);
          if (s == 0)      Qh[((size_t)((bb * 16 + hh) * 2048 + t)) * 64 + d] = o;
          else if (s == 1) Kh[((size_t)((bb * 16 + hh) * 2048 + t)) * 64 + d] = o;
          else             Vt[((size_t)((bb * 16 + hh) * 64 + d)) * 2048 + t] = o;
        }
      }
    }
  } else {
    #pragma unroll
    for (int j = 0; j < 4; ++j) {
      const int n = bx * 128 + wc * 64 + j * 16 + l15;
      const float bj = bias[n];
      #pragma unroll
      for (int i = 0; i < 4; ++i)
        #pragma unroll
        for (int r = 0; r < 4; ++r) {
          const int m = by * 128 + wr * 64 + i * 16 + l4 * 4 + r;
          Out[(size_t)m * 1024 + n] = acc[i][j][r] + bj;
        }
    }
  }
}

// ---------------- flash attention (causal), head-major inputs ----------------
// 4096 blocks, 256 threads = 4 waves. ONE q-tile (32 rows) per block; the
// tile's kt range (0..qi, KT=32) is split 4 ways by kt mod 4 -> per-wave depth
// balanced within +-1 (R12 lesson: the old 2-tile pairing left short-tile
// waves idling at the merge barrier, ~33% of residency wasted).
// bid->(b,h): all 64 blocks of one head pinned to one XCD (bid&7).
// Inner loop = R10's plain-C++ body (asm pipeline regressed: lost occupancy).
// 4-way merge through LDS: roles 1..3 write partials, role 0 combines.
__global__ __launch_bounds__(256, 3)
void k_attn(const bf16* __restrict__ Qh, const bf16* __restrict__ Kh,
            const bf16* __restrict__ Vt, bf16* __restrict__ Ao)
{
  __shared__ unsigned int smem[6336];   // 25344 B: 3 merge regions (64x33 u32); aliased by 4 P-tiles (32x40 bf16)
  const int tid = threadIdx.x;
  const int wv = tid >> 6, lane = tid & 63;
  const int l4 = lane >> 4, l15 = lane & 15;

  const int bid = blockIdx.x;
  const int xcd = bid & 7;
  const int idx = bid >> 3;            // 0..511
  const int qi  = idx & 63;            // q-tile 0..63
  const int grp = idx >> 6;            // 0..7
  const int bh  = grp * 8 + xcd;       // all blocks of a head share an XCD
  const int b = bh >> 4, h = bh & 15;

  const int role = (wv + bid) & 3;     // rotate roles across SIMDs; role = kt phase
  const int qbase = qi * 32;

  const bf16* Qp = Qh + (size_t)bh * 2048 * 64;
  const bf16* Kp = Kh + (size_t)bh * 2048 * 64;
  const bf16* Vp = Vt + (size_t)bh * 64 * 2048;
  bf16* Pw = (bf16*)smem + wv * (32 * 40);

  bf16x8 qa[2][2];
  #pragma unroll
  for (int i = 0; i < 2; ++i)
    #pragma unroll
    for (int kh = 0; kh < 2; ++kh)
      qa[i][kh] = *reinterpret_cast<const bf16x8*>(
          Qp + (size_t)(qbase + i * 16 + l15) * 64 + kh * 32 + l4 * 8);

  f32x4 o[2][4];
  float mr[2], lr[2];                  // per-lane: q = qbase + i*16 + l15
  #pragma unroll
  for (int i = 0; i < 2; ++i) {
    #pragma unroll
    for (int jd = 0; jd < 4; ++jd) o[i][jd] = f32x4{0.f, 0.f, 0.f, 0.f};
    mr[i] = -1e30f; lr[i] = 0.f;
  }

  const int ktmax = qi;                // KT=32: (qbase+31)>>5 == qi

  // prologue: K fragments for first kt (clamped; waves with role>ktmax skip loop)
  const int kt0 = (role <= ktmax) ? role : ktmax;
  bf16x8 kbf[2][2];
  #pragma unroll
  for (int j = 0; j < 2; ++j)
    #pragma unroll
    for (int kh = 0; kh < 2; ++kh)
      kbf[j][kh] = *reinterpret_cast<const bf16x8*>(
          Kp + (size_t)(kt0 * 32 + j * 16 + l15) * 64 + kh * 32 + l4 * 8);

  for (int kt = role; kt <= ktmax; kt += 4) {
    const bool full = (kt * 32 + 31) <= qbase;

    // swapped QK^T: s[i][j][r] = S[q = qbase+i*16+l15][k = kt*32+j*16+l4*4+r]
    f32x4 s[2][2];
    #pragma unroll
    for (int i = 0; i < 2; ++i)
      #pragma unroll
      for (int j = 0; j < 2; ++j) s[i][j] = f32x4{0.f, 0.f, 0.f, 0.f};
    #pragma unroll
    for (int j = 0; j < 2; ++j)
      #pragma unroll
      for (int i = 0; i < 2; ++i) {
        s[i][j] = __builtin_amdgcn_mfma_f32_16x16x32_bf16(kbf[j][0], qa[i][0], s[i][j], 0, 0, 0);
        s[i][j] = __builtin_amdgcn_mfma_f32_16x16x32_bf16(kbf[j][1], qa[i][1], s[i][j], 0, 0, 0);
      }

    // V loads issued now: latency hides under the softmax VALU chain
    bf16x8 vbf[4];
    #pragma unroll
    for (int jd = 0; jd < 4; ++jd)
      vbf[jd] = *reinterpret_cast<const bf16x8*>(
          Vp + (size_t)(jd * 16 + l15) * 2048 + kt * 32 + l4 * 8);

    // scale (log2e folded) + causal mask; q is lane-uniform per i
    #pragma unroll
    for (int i = 0; i < 2; ++i) {
      const int q = qbase + i * 16 + l15;
      #pragma unroll
      for (int j = 0; j < 2; ++j)
        #pragma unroll
        for (int r = 0; r < 4; ++r) {
          float v = s[i][j][r] * 0.18033688f;   // 0.125 * log2(e)
          if (!full) {
            const int kk = kt * 32 + j * 16 + l4 * 4 + r;
            if (kk > q) v = -1e30f;
          }
          s[i][j][r] = v;
        }
    }

    // lane-local softmax per i (row q), exp2 domain, defer-max THR=8
    #pragma unroll
    for (int i = 0; i < 2; ++i) {
      float mx = s[i][0][0];
      #pragma unroll
      for (int j = 0; j < 2; ++j)
        #pragma unroll
        for (int r = 0; r < 4; ++r)
          if (j + r > 0) mx = fmaxf(mx, s[i][j][r]);
      mx = fmaxf(mx, __shfl_xor(mx, 16));
      mx = fmaxf(mx, __shfl_xor(mx, 32));
      if (__any(mx > mr[i] + 8.f)) {        // rescale only when max grows materially
        const float mn = fmaxf(mr[i], mx);
        const float al = ex2(mr[i] - mn);
        mr[i] = mn;
        lr[i] *= al;
        float albc[4];
        #pragma unroll
        for (int r = 0; r < 4; ++r) albc[r] = __shfl(al, l4 * 4 + r);
        #pragma unroll
        for (int jd = 0; jd < 4; ++jd)
          #pragma unroll
          for (int r = 0; r < 4; ++r) o[i][jd][r] *= albc[r];
      }
      float ps = 0.f;
      #pragma unroll
      for (int j = 0; j < 2; ++j) {
        const float p0 = ex2(s[i][j][0] - mr[i]);
        const float p1 = ex2(s[i][j][1] - mr[i]);
        const float p2 = ex2(s[i][j][2] - mr[i]);
        const float p3 = ex2(s[i][j][3] - mr[i]);
        ps += (p0 + p1) + (p2 + p3);
        const unsigned int u0 = (unsigned int)f2b(p0) | ((unsigned int)f2b(p1) << 16);
        const unsigned int u1 = (unsigned int)f2b(p2) | ((unsigned int)f2b(p3) << 16);
        *reinterpret_cast<uint2*>(Pw + (i * 16 + l15) * 40 + j * 16 + l4 * 4) =
            make_uint2(u0, u1);
      }
      ps += __shfl_xor(ps, 16);
      ps += __shfl_xor(ps, 32);
      lr[i] += ps;
    }

    // K prefetch for kt+4 (clamped)
    const int ktn = (kt + 4 <= ktmax) ? (kt + 4) : ktmax;
    #pragma unroll
    for (int j = 0; j < 2; ++j)
      #pragma unroll
      for (int kh = 0; kh < 2; ++kh)
        kbf[j][kh] = *reinterpret_cast<const bf16x8*>(
            Kp + (size_t)(ktn * 32 + j * 16 + l15) * 64 + kh * 32 + l4 * 8);

    // PV: A-frags from P LDS (single kh at KT=32), B-frags from transposed V
    bf16x8 pa[2];
    #pragma unroll
    for (int i = 0; i < 2; ++i)
      pa[i] = *reinterpret_cast<const bf16x8*>(Pw + (i * 16 + l15) * 40 + l4 * 8);
    #pragma unroll
    for (int jd = 0; jd < 4; ++jd)
      #pragma unroll
      for (int i = 0; i < 2; ++i)
        o[i][jd] = __builtin_amdgcn_mfma_f32_16x16x32_bf16(pa[i], vbf[jd], o[i][jd], 0, 0, 0);
  }

  // convert m/l to O's C-layout domain (q_local = l4*4 + r) for the merge
  float mrv[2][4], lrv[2][4];
  #pragma unroll
  for (int i = 0; i < 2; ++i)
    #pragma unroll
    for (int r = 0; r < 4; ++r) {
      mrv[i][r] = __shfl(mr[i], l4 * 4 + r);
      lrv[i][r] = __shfl(lr[i], l4 * 4 + r);
    }

  // ---- 4-way merge through LDS (aliases dead P buffers) ----
  __syncthreads();
  if (role != 0) {                    // writers: roles 1..3 -> region role-1
    unsigned int* p = smem + (role - 1) * (64 * 33) + lane * 33;
    #pragma unroll
    for (int i = 0; i < 2; ++i)
      #pragma unroll
      for (int r = 0; r < 4; ++r) {
        p[i * 4 + r]     = __builtin_bit_cast(unsigned int, mrv[i][r]);
        p[8 + i * 4 + r] = __builtin_bit_cast(unsigned int, lrv[i][r]);
      }
    #pragma unroll
    for (int i = 0; i < 2; ++i)
      #pragma unroll
      for (int jd = 0; jd < 4; ++jd)
        #pragma unroll
        for (int rp = 0; rp < 2; ++rp) {
          unsigned int lo = f2b(o[i][jd][2 * rp]);
          unsigned int hi = f2b(o[i][jd][2 * rp + 1]);
          p[16 + (i * 4 + jd) * 2 + rp] = lo | (hi << 16);
        }
  }
  __syncthreads();
  if (role == 0) {                    // combiner
    const unsigned int* p0 = smem + 0 * (64 * 33) + lane * 33;
    const unsigned int* p1 = smem + 1 * (64 * 33) + lane * 33;
    const unsigned int* p2 = smem + 2 * (64 * 33) + lane * 33;
    #pragma unroll
    for (int i = 0; i < 2; ++i)
      #pragma unroll
      for (int r = 0; r < 4; ++r) {
        const float m1 = __builtin_bit_cast(float, p0[i * 4 + r]);
        const float m2 = __builtin_bit_cast(float, p1[i * 4 + r]);
        const float m3 = __builtin_bit_cast(float, p2[i * 4 + r]);
        const float l1 = __builtin_bit_cast(float, p0[8 + i * 4 + r]);
        const float l2 = __builtin_bit_cast(float, p1[8 + i * 4 + r]);
        const float l3 = __builtin_bit_cast(float, p2[8 + i * 4 + r]);
        const float mm = fmaxf(fmaxf(mrv[i][r], m1), fmaxf(m2, m3));
        const float a0 = ex2(mrv[i][r] - mm);
        const float a1 = ex2(m1 - mm);
        const float a2 = ex2(m2 - mm);
        const float a3 = ex2(m3 - mm);
        const float inv = 1.f / (lrv[i][r] * a0 + l1 * a1 + l2 * a2 + l3 * a3);
        const int q = qbase + i * 16 + l4 * 4 + r;
        #pragma unroll
        for (int jd = 0; jd < 4; ++jd) {
          const int ui = 16 + (i * 4 + jd) * 2 + (r >> 1);
          const bool hi = (r & 1);
          const float o1 = b2f(hi ? (p0[ui] >> 16) : (p0[ui] & 0xffffu));
          const float o2 = b2f(hi ? (p1[ui] >> 16) : (p1[ui] & 0xffffu));
          const float o3 = b2f(hi ? (p2[ui] >> 16) : (p2[ui] & 0xffffu));
          const float val = (o[i][jd][r] * a0 + o1 * a1 + o2 * a2 + o3 * a3) * inv;
          Ao[(size_t)(b * 2048 + q) * 1024 + h * 64 + jd * 16 + l15] = __float2bfloat16(val);
        }
      }
  }
}

extern "C" void kernel_launch(void* const* d_in, const int* in_sizes, int n_in,
                              void* d_out, int out_size, void* d_ws, size_t ws_size,
                              hipStream_t stream)
{
  const float* x     = (const float*)d_in[0];
  const float* W_qkv = (const float*)d_in[1];
  const float* b_qkv = (const float*)d_in[2];
  const float* W_fc  = (const float*)d_in[3];
  const float* b_fc  = (const float*)d_in[4];
  float* out = (float*)d_out;

  char* ws = (char*)d_ws;
  bf16* x_bf = (bf16*)ws;  ws += (size_t)8192 * 1024 * 2;            // 16 MB
  bf16* Wqt  = (bf16*)ws;  ws += (size_t)3072 * 1024 * 2;            //  6 MB
  bf16* Wft  = (bf16*)ws;  ws += (size_t)1024 * 1024 * 2;            //  2 MB
  bf16* Qh   = (bf16*)ws;  ws += (size_t)4 * 16 * 2048 * 64 * 2;     // 16 MB
  bf16* Kh   = (bf16*)ws;  ws += (size_t)4 * 16 * 2048 * 64 * 2;     // 16 MB
  bf16* Vt   = (bf16*)ws;  ws += (size_t)4 * 16 * 64 * 2048 * 2;     // 16 MB
  bf16* Ao   = (bf16*)ws;  ws += (size_t)8192 * 1024 * 2;            // 16 MB  (total 88 MB)

  k_convert<<<8192, 256, 0, stream>>>(x, (unsigned short*)x_bf, 8192 * 1024 / 4);
  k_transpose<<<dim3(3072 / 32, 1024 / 32), dim3(32, 8), 0, stream>>>(W_qkv, Wqt, 1024, 3072);
  k_transpose<<<dim3(1024 / 32, 1024 / 32), dim3(32, 8), 0, stream>>>(W_fc, Wft, 1024, 1024);
  k_gemm<0><<<dim3(24, 64), 256, 0, stream>>>(x_bf, Wqt, b_qkv, Qh, Kh, Vt, nullptr);
  k_attn<<<4096, 256, 0, stream>>>(Qh, Kh, Vt, Ao);
  k_gemm<1><<<dim3(8, 64), 256, 0, stream>>>(Ao, Wft, b_fc, nullptr, nullptr, nullptr, out);
}

// Round 14
// 265.845 us; speedup vs baseline: 1.0903x; 1.0903x over previous
//
#include <hip/hip_runtime.h>
#include <hip/hip_bf16.h>

typedef __hip_bfloat16 bf16;
typedef short bf16x8 __attribute__((ext_vector_type(8)));
typedef float f32x4 __attribute__((ext_vector_type(4)));

// B=4, T=2048, D=1024, H=16, HD=64

static __device__ __forceinline__ void glds16(const bf16* g, bf16* l) {
  __builtin_amdgcn_global_load_lds(
      (const __attribute__((address_space(1))) void*)g,
      (__attribute__((address_space(3))) void*)l, 16, 0, 0);
}

static __device__ __forceinline__ unsigned short f2b(float f) {
  return __builtin_bit_cast(unsigned short, __float2bfloat16(f));
}
static __device__ __forceinline__ float b2f(unsigned int u16bits) {
  return __builtin_bit_cast(float, u16bits << 16);
}
// 2^x via the clang builtin (lowers to v_exp_f32 with compiler-managed hazards)
static __device__ __forceinline__ float ex2(float x) {
  return __builtin_amdgcn_exp2f(x);
}

// ---------------- fp32 -> bf16 convert, 4 elems/thread ----------------
__global__ void k_convert(const float* __restrict__ in, unsigned short* __restrict__ out, int n4) {
  int i = blockIdx.x * 256 + threadIdx.x;
  if (i >= n4) return;
  float4 v = reinterpret_cast<const float4*>(in)[i];
  ushort4 o;
  o.x = f2b(v.x); o.y = f2b(v.y); o.z = f2b(v.z); o.w = f2b(v.w);
  reinterpret_cast<ushort4*>(out)[i] = o;
}

// ---------------- transpose R x C fp32  ->  C x R bf16 ----------------
__global__ void k_transpose(const float* __restrict__ in, bf16* __restrict__ out, int R, int C) {
  __shared__ float t[32][33];
  int c0 = blockIdx.x * 32, r0 = blockIdx.y * 32;
  int tx = threadIdx.x, ty = threadIdx.y;  // block (32,8)
  #pragma unroll
  for (int j = 0; j < 32; j += 8)
    t[ty + j][tx] = in[(size_t)(r0 + ty + j) * C + c0 + tx];
  __syncthreads();
  #pragma unroll
  for (int j = 0; j < 32; j += 8)
    out[(size_t)(c0 + ty + j) * R + r0 + tx] = __float2bfloat16(t[tx][ty + j]);
}

// ---------------- GEMM: C = A(M x 1024) * Bt(N x 1024)^T + bias ----------------
// BK=64 (R13 change): halves barrier count vs BK=32 (the ~20% barrier-drain
// stall of this 2-phase structure). Row stride 128B would be a 16-way bank
// conflict on ds_read_b128, so staging uses the both-sides XOR swizzle:
// glds dest stays linear, GLOBAL source granule is pre-swizzled
// ((l&7)^(l>>3&7)), fragment reads XOR granule with (row&7) -> 2-way max.
// EPI 0: scatter to Qh/Kh[b][h][t][d], Vt[b][h][d][t] (bf16, +b_qkv);
//        Q pre-scaled by 0.125*log2(e) for the exp2-domain attention.
// EPI 1: Out fp32 [m][1024] (+b_fc)
template<int EPI>
__global__ __launch_bounds__(256, 2)
void k_gemm(const bf16* __restrict__ A, const bf16* __restrict__ Bt,
            const float* __restrict__ bias,
            bf16* __restrict__ Qh, bf16* __restrict__ Kh, bf16* __restrict__ Vt,
            float* __restrict__ Out)
{
  constexpr int K = 1024;
  __shared__ bf16 sA[128 * 64];
  __shared__ bf16 sB[128 * 64];
  const int tid = threadIdx.x;
  const int wv = tid >> 6, lane = tid & 63;
  const int wr = wv >> 1, wc = wv & 1;
  const int l4 = lane >> 4, l15 = lane & 15;

  // XCD-aware bijective swizzle (nwg % 8 == 0 for both grids: 1536, 512)
  const int nbx = gridDim.x;
  const int nwg = nbx * gridDim.y;
  const int flat = blockIdx.y * nbx + blockIdx.x;
  const int cpx = nwg >> 3;
  const int swz = (flat & 7) * cpx + (flat >> 3);
  const int bx = swz % nbx;
  const int by = swz / nbx;

  // staging: 4 glds calls/operand/iter; each call = 32 rows x 128B.
  // lane covers row (wv*8 + l>>3), granule (l&7); source granule XOR (row&7).
  const int srow8 = lane >> 3;                    // 0..7 within wave's 8 rows
  const int sgran = (lane & 7) ^ srow8;           // pre-swizzled source granule
  const bf16* gA0 = A  + (size_t)(by * 128 + wv * 8 + srow8) * K + sgran * 8;
  const bf16* gB0 = Bt + (size_t)(bx * 128 + wv * 8 + srow8) * K + sgran * 8;
  bf16* lA0 = sA + wv * 8 * 64;                   // wave-uniform; HW adds lane*16B
  bf16* lB0 = sB + wv * 8 * 64;

  f32x4 acc[4][4];
  #pragma unroll
  for (int i = 0; i < 4; ++i)
    #pragma unroll
    for (int j = 0; j < 4; ++j) acc[i][j] = f32x4{0.f, 0.f, 0.f, 0.f};

  for (int kb = 0; kb < K; kb += 64) {
    #pragma unroll
    for (int c = 0; c < 4; ++c) {
      glds16(gA0 + kb + (size_t)(c * 32) * K, lA0 + c * 32 * 64);
      glds16(gB0 + kb + (size_t)(c * 32) * K, lB0 + c * 32 * 64);
    }
    __syncthreads();
    #pragma unroll
    for (int kk = 0; kk < 2; ++kk) {
      bf16x8 af[4], bfr[4];
      #pragma unroll
      for (int i = 0; i < 4; ++i) {
        const int R = wr * 64 + i * 16 + l15;
        af[i] = *reinterpret_cast<const bf16x8*>(
            sA + R * 64 + (((kk * 4 + l4) ^ (R & 7)) * 8));
      }
      #pragma unroll
      for (int j = 0; j < 4; ++j) {
        const int R = wc * 64 + j * 16 + l15;
        bfr[j] = *reinterpret_cast<const bf16x8*>(
            sB + R * 64 + (((kk * 4 + l4) ^ (R & 7)) * 8));
      }
      #pragma unroll
      for (int i = 0; i < 4; ++i)
        #pragma unroll
        for (int j = 0; j < 4; ++j)
          acc[i][j] = __builtin_amdgcn_mfma_f32_16x16x32_bf16(af[i], bfr[j], acc[i][j], 0, 0, 0);
    }
    __syncthreads();
  }

  if (EPI == 0) {
    #pragma unroll
    for (int j = 0; j < 4; ++j) {
      const int n = bx * 128 + wc * 64 + j * 16 + l15;
      const float bj = bias[n];
      const int s = n >> 10;
      const int hh = (n >> 6) & 15;
      const int d = n & 63;
      #pragma unroll
      for (int i = 0; i < 4; ++i) {
        #pragma unroll
        for (int r = 0; r < 4; ++r) {
          const int m = by * 128 + wr * 64 + i * 16 + l4 * 4 + r;
          const int bb = m >> 11, t = m & 2047;
          float of = acc[i][j][r] + bj;
          if (s == 0) of *= 0.18033688f;  // 1/8 * log2(e), exp2-domain attention
          const bf16 o = __float2bfloat16(of);
          if (s == 0)      Qh[((size_t)((bb * 16 + hh) * 2048 + t)) * 64 + d] = o;
          else if (s == 1) Kh[((size_t)((bb * 16 + hh) * 2048 + t)) * 64 + d] = o;
          else             Vt[((size_t)((bb * 16 + hh) * 64 + d)) * 2048 + t] = o;
        }
      }
    }
  } else {
    #pragma unroll
    for (int j = 0; j < 4; ++j) {
      const int n = bx * 128 + wc * 64 + j * 16 + l15;
      const float bj = bias[n];
      #pragma unroll
      for (int i = 0; i < 4; ++i)
        #pragma unroll
        for (int r = 0; r < 4; ++r) {
          const int m = by * 128 + wr * 64 + i * 16 + l4 * 4 + r;
          Out[(size_t)m * 1024 + n] = acc[i][j][r] + bj;
        }
    }
  }
}

// ---------------- flash attention (causal), head-major inputs ----------------
// R10 version, reverted byte-exact (145 us verified; R11-R13 restructures all
// regressed). 2048 blocks, 4 waves; q-tile pair (g, 63-g), even/odd kt split,
// KT=32, swapped QK^T lane-local softmax, defer-max THR=8, LDS merge.
// NOTE: Q arrives pre-scaled by 0.125*log2(e) (folded into GEMM epilogue).
__global__ __launch_bounds__(256, 3)
void k_attn(const bf16* __restrict__ Qh, const bf16* __restrict__ Kh,
            const bf16* __restrict__ Vt, bf16* __restrict__ Ao)
{
  __shared__ unsigned int smem[4608];   // 18432 B: 4 P-tiles (32x40 bf16) aliased by 2 combine regions (64x33 u32)
  const int tid = threadIdx.x;
  const int wv = tid >> 6, lane = tid & 63;
  const int l4 = lane >> 4, l15 = lane & 15;

  const int bid = blockIdx.x;
  const int xcd = bid & 7;
  const int idx = bid >> 3;            // 0..255
  const int g   = idx & 31;
  const int grp = idx >> 5;            // 0..7
  const int bh  = grp * 8 + xcd;       // all g-blocks of a head share an XCD
  const int b = bh >> 4, h = bh & 15;

  const int role = (wv + bid) & 3;     // rotate roles across SIMDs
  const int qi = (role < 2) ? g : (63 - g);
  const int parity = role & 1;
  const int qbase = qi * 32;

  const bf16* Qp = Qh + (size_t)bh * 2048 * 64;
  const bf16* Kp = Kh + (size_t)bh * 2048 * 64;
  const bf16* Vp = Vt + (size_t)bh * 64 * 2048;
  bf16* Pw = (bf16*)smem + wv * (32 * 40);

  bf16x8 qa[2][2];
  #pragma unroll
  for (int i = 0; i < 2; ++i)
    #pragma unroll
    for (int kh = 0; kh < 2; ++kh)
      qa[i][kh] = *reinterpret_cast<const bf16x8*>(
          Qp + (size_t)(qbase + i * 16 + l15) * 64 + kh * 32 + l4 * 8);

  f32x4 o[2][4];
  float mr[2], lr[2];                  // per-lane: q = qbase + i*16 + l15
  #pragma unroll
  for (int i = 0; i < 2; ++i) {
    #pragma unroll
    for (int jd = 0; jd < 4; ++jd) o[i][jd] = f32x4{0.f, 0.f, 0.f, 0.f};
    mr[i] = -1e30f; lr[i] = 0.f;
  }

  const int ktmax = (qbase + 31) >> 5;   // KT=32 granularity

  // prologue: K fragments for first kt (clamped; waves with parity>ktmax skip loop)
  const int kt0 = (parity <= ktmax) ? parity : ktmax;
  bf16x8 kbf[2][2];
  #pragma unroll
  for (int j = 0; j < 2; ++j)
    #pragma unroll
    for (int kh = 0; kh < 2; ++kh)
      kbf[j][kh] = *reinterpret_cast<const bf16x8*>(
          Kp + (size_t)(kt0 * 32 + j * 16 + l15) * 64 + kh * 32 + l4 * 8);

  for (int kt = parity; kt <= ktmax; kt += 2) {
    const bool full = (kt * 32 + 31) <= qbase;

    // swapped QK^T: s[i][j][r] = S[q = qbase+i*16+l15][k = kt*32+j*16+l4*4+r]
    f32x4 s[2][2];
    #pragma unroll
    for (int i = 0; i < 2; ++i)
      #pragma unroll
      for (int j = 0; j < 2; ++j) s[i][j] = f32x4{0.f, 0.f, 0.f, 0.f};
    #pragma unroll
    for (int j = 0; j < 2; ++j)
      #pragma unroll
      for (int i = 0; i < 2; ++i) {
        s[i][j] = __builtin_amdgcn_mfma_f32_16x16x32_bf16(kbf[j][0], qa[i][0], s[i][j], 0, 0, 0);
        s[i][j] = __builtin_amdgcn_mfma_f32_16x16x32_bf16(kbf[j][1], qa[i][1], s[i][j], 0, 0, 0);
      }

    // V loads issued now: latency hides under the softmax VALU chain (KT=32 -> single kh)
    bf16x8 vbf[4];
    #pragma unroll
    for (int jd = 0; jd < 4; ++jd)
      vbf[jd] = *reinterpret_cast<const bf16x8*>(
          Vp + (size_t)(jd * 16 + l15) * 2048 + kt * 32 + l4 * 8);

    // causal mask; logits already log2-scaled (folded into Q)
    #pragma unroll
    for (int i = 0; i < 2; ++i) {
      const int q = qbase + i * 16 + l15;
      #pragma unroll
      for (int j = 0; j < 2; ++j)
        #pragma unroll
        for (int r = 0; r < 4; ++r) {
          float v = s[i][j][r];
          if (!full) {
            const int kk = kt * 32 + j * 16 + l4 * 4 + r;
            if (kk > q) v = -1e30f;
          }
          s[i][j][r] = v;
        }
    }

    // lane-local softmax per i (row q), exp2 domain, defer-max THR=8
    #pragma unroll
    for (int i = 0; i < 2; ++i) {
      float mx = s[i][0][0];
      #pragma unroll
      for (int j = 0; j < 2; ++j)
        #pragma unroll
        for (int r = 0; r < 4; ++r)
          if (j + r > 0) mx = fmaxf(mx, s[i][j][r]);
      mx = fmaxf(mx, __shfl_xor(mx, 16));
      mx = fmaxf(mx, __shfl_xor(mx, 32));
      if (__any(mx > mr[i] + 8.f)) {        // rescale only when max grows materially
        const float mn = fmaxf(mr[i], mx);
        const float al = ex2(mr[i] - mn);
        mr[i] = mn;
        lr[i] *= al;
        float albc[4];
        #pragma unroll
        for (int r = 0; r < 4; ++r) albc[r] = __shfl(al, l4 * 4 + r);
        #pragma unroll
        for (int jd = 0; jd < 4; ++jd)
          #pragma unroll
          for (int r = 0; r < 4; ++r) o[i][jd][r] *= albc[r];
      }
      float ps = 0.f;
      #pragma unroll
      for (int j = 0; j < 2; ++j) {
        const float p0 = ex2(s[i][j][0] - mr[i]);
        const float p1 = ex2(s[i][j][1] - mr[i]);
        const float p2 = ex2(s[i][j][2] - mr[i]);
        const float p3 = ex2(s[i][j][3] - mr[i]);
        ps += (p0 + p1) + (p2 + p3);
        const unsigned int u0 = (unsigned int)f2b(p0) | ((unsigned int)f2b(p1) << 16);
        const unsigned int u1 = (unsigned int)f2b(p2) | ((unsigned int)f2b(p3) << 16);
        *reinterpret_cast<uint2*>(Pw + (i * 16 + l15) * 40 + j * 16 + l4 * 4) =
            make_uint2(u0, u1);
      }
      ps += __shfl_xor(ps, 16);
      ps += __shfl_xor(ps, 32);
      lr[i] += ps;
    }

    // K prefetch for kt+2 (clamped)
    const int ktn = (kt + 2 <= ktmax) ? (kt + 2) : ktmax;
    #pragma unroll
    for (int j = 0; j < 2; ++j)
      #pragma unroll
      for (int kh = 0; kh < 2; ++kh)
        kbf[j][kh] = *reinterpret_cast<const bf16x8*>(
            Kp + (size_t)(ktn * 32 + j * 16 + l15) * 64 + kh * 32 + l4 * 8);

    // PV: A-frags from P LDS (single kh at KT=32), B-frags from transposed V
    bf16x8 pa[2];
    #pragma unroll
    for (int i = 0; i < 2; ++i)
      pa[i] = *reinterpret_cast<const bf16x8*>(Pw + (i * 16 + l15) * 40 + l4 * 8);
    #pragma unroll
    for (int jd = 0; jd < 4; ++jd)
      #pragma unroll
      for (int i = 0; i < 2; ++i)
        o[i][jd] = __builtin_amdgcn_mfma_f32_16x16x32_bf16(pa[i], vbf[jd], o[i][jd], 0, 0, 0);
  }

  // convert m/l to O's C-layout domain (q_local = l4*4 + r) for the merge
  float mrv[2][4], lrv[2][4];
  #pragma unroll
  for (int i = 0; i < 2; ++i)
    #pragma unroll
    for (int r = 0; r < 4; ++r) {
      mrv[i][r] = __shfl(mr[i], l4 * 4 + r);
      lrv[i][r] = __shfl(lr[i], l4 * 4 + r);
    }

  // ---- merge even/odd partials through LDS (aliases dead P buffers) ----
  __syncthreads();
  unsigned int* reg0 = smem;          // 64 lanes x 33 u32 (stride 33 avoids bank conflicts)
  unsigned int* reg1 = smem + 64 * 33;
  if (parity == 1) {                  // writers: roles 1 (tile g) and 3 (tile 63-g)
    unsigned int* p = ((role == 1) ? reg0 : reg1) + lane * 33;
    #pragma unroll
    for (int i = 0; i < 2; ++i)
      #pragma unroll
      for (int r = 0; r < 4; ++r) {
        p[i * 4 + r]     = __builtin_bit_cast(unsigned int, mrv[i][r]);
        p[8 + i * 4 + r] = __builtin_bit_cast(unsigned int, lrv[i][r]);
      }
    #pragma unroll
    for (int i = 0; i < 2; ++i)
      #pragma unroll
      for (int jd = 0; jd < 4; ++jd)
        #pragma unroll
        for (int rp = 0; rp < 2; ++rp) {
          unsigned int lo = f2b(o[i][jd][2 * rp]);
          unsigned int hi = f2b(o[i][jd][2 * rp + 1]);
          p[16 + (i * 4 + jd) * 2 + rp] = lo | (hi << 16);
        }
  }
  __syncthreads();
  if (parity == 0) {                  // readers: roles 0 and 2
    const unsigned int* p = ((role == 0) ? reg0 : reg1) + lane * 33;
    #pragma unroll
    for (int i = 0; i < 2; ++i)
      #pragma unroll
      for (int r = 0; r < 4; ++r) {
        const float m1 = __builtin_bit_cast(float, p[i * 4 + r]);
        const float l1 = __builtin_bit_cast(float, p[8 + i * 4 + r]);
        const float mm = fmaxf(mrv[i][r], m1);
        const float a0 = ex2(mrv[i][r] - mm);
        const float a1 = ex2(m1 - mm);
        const float inv = 1.f / (lrv[i][r] * a0 + l1 * a1);
        const int q = qbase + i * 16 + l4 * 4 + r;
        #pragma unroll
        for (int jd = 0; jd < 4; ++jd) {
          const unsigned int u = p[16 + (i * 4 + jd) * 2 + (r >> 1)];
          const float o1 = b2f((r & 1) ? (u >> 16) : (u & 0xffffu));
          const float val = (o[i][jd][r] * a0 + o1 * a1) * inv;
          Ao[(size_t)(b * 2048 + q) * 1024 + h * 64 + jd * 16 + l15] = __float2bfloat16(val);
        }
      }
  }
}

extern "C" void kernel_launch(void* const* d_in, const int* in_sizes, int n_in,
                              void* d_out, int out_size, void* d_ws, size_t ws_size,
                              hipStream_t stream)
{
  const float* x     = (const float*)d_in[0];
  const float* W_qkv = (const float*)d_in[1];
  const float* b_qkv = (const float*)d_in[2];
  const float* W_fc  = (const float*)d_in[3];
  const float* b_fc  = (const float*)d_in[4];
  float* out = (float*)d_out;

  char* ws = (char*)d_ws;
  bf16* x_bf = (bf16*)ws;  ws += (size_t)8192 * 1024 * 2;            // 16 MB
  bf16* Wqt  = (bf16*)ws;  ws += (size_t)3072 * 1024 * 2;            //  6 MB
  bf16* Wft  = (bf16*)ws;  ws += (size_t)1024 * 1024 * 2;            //  2 MB
  bf16* Qh   = (bf16*)ws;  ws += (size_t)4 * 16 * 2048 * 64 * 2;     // 16 MB
  bf16* Kh   = (bf16*)ws;  ws += (size_t)4 * 16 * 2048 * 64 * 2;     // 16 MB
  bf16* Vt   = (bf16*)ws;  ws += (size_t)4 * 16 * 64 * 2048 * 2;     // 16 MB
  bf16* Ao   = (bf16*)ws;  ws += (size_t)8192 * 1024 * 2;            // 16 MB  (total 88 MB)

  k_convert<<<8192, 256, 0, stream>>>(x, (unsigned short*)x_bf, 8192 * 1024 / 4);
  k_transpose<<<dim3(3072 / 32, 1024 / 32), dim3(32, 8), 0, stream>>>(W_qkv, Wqt, 1024, 3072);
  k_transpose<<<dim3(1024 / 32, 1024 / 32), dim3(32, 8), 0, stream>>>(W_fc, Wft, 1024, 1024);
  k_gemm<0><<<dim3(24, 64), 256, 0, stream>>>(x_bf, Wqt, b_qkv, Qh, Kh, Vt, nullptr);
  k_attn<<<2048, 256, 0, stream>>>(Qh, Kh, Vt, Ao);
  k_gemm<1><<<dim3(8, 64), 256, 0, stream>>>(Ao, Wft, b_fc, nullptr, nullptr, nullptr, out);
}